// Round 3
// baseline (7668.951 us; speedup 1.0000x reference)
//
#include <hip/hip_runtime.h>

// LatentGuidedEdgeDecoder — round 3: CORRECTNESS-FIRST, runtime dtype dispatch.
// R1 (bf16 reads) -> NaN == f32-as-bf16 misread; R2 (f32 reads) -> finite 3.5 ==
// bf16-as-f32 misread (or bf16-out into f32 buffer). Same algebra audits clean both
// ways => dtype is the unknown. Resolve it ON DEVICE: k_detect classifies node_i's
// raw words (bf16 exponents vs f32 mantissa bits), writes flag to ws; every kernel
// is templated <T,WANT> and early-exits unless flag matches. Both variants are
// launched every call (graph-capture-safe, same work each call).
// Compute kernel: one block per row, 256 threads, all-f32 math, thread-per-output
// (coalesced weight reads), LDS only for stage vectors + LN reductions.

typedef __bf16 bf16;
#define HD 256

template <class T>
__device__ __forceinline__ float ld(const T* __restrict__ p) { return (float)*p; }

// ---------------- dtype detector ----------------
// bf16 data: word bits[14:7] = exponent of element 2i of ~N(0,1) -> in [110,140] ~100%.
// f32 data:  word bits[14:7] = mid-mantissa bits -> ~uniform -> in-range ~12%.
__global__ void k_detect(const unsigned int* __restrict__ w, int* __restrict__ flag) {
  __shared__ int sRed[4];
  int t = threadIdx.x;  // 256 threads
  int cnt = 0;
  for (int i = t; i < 16384; i += 256) {
    unsigned e = (w[i] >> 7) & 0xFFu;
    cnt += (e >= 110u && e <= 140u) ? 1 : 0;
  }
#pragma unroll
  for (int m = 1; m < 64; m <<= 1) cnt += __shfl_xor(cnt, m);
  if ((t & 63) == 0) sRed[t >> 6] = cnt;
  __syncthreads();
  if (t == 0) flag[0] = (sRed[0] + sRed[1] + sRed[2] + sRed[3] > 8192) ? 1 : 0;
}

// ---------------- attention collapse precompute ----------------
// softmax over a single key == 1 exactly -> attended = LN(latent @ (Wc@Wv@Wo) + bcvo).
// tmp[i<8][m] = (Wc@Wv)[i][m]; tmp[8][m] = (bc@Wv + bv)[m]
template <class T, int WANT>
__global__ void k_cvo_a(const int* __restrict__ flag, const T* __restrict__ Wc,
                        const T* __restrict__ Wv, const T* __restrict__ bc,
                        const T* __restrict__ bv, float* __restrict__ tmp) {
  if (*flag != WANT) return;
  int i = blockIdx.x;   // 0..8
  int m = threadIdx.x;  // 0..255
  float s = 0.f;
  if (i < 8) {
    for (int u = 0; u < 256; ++u) s += ld(Wc + i * 256 + u) * ld(Wv + (size_t)u * 256 + m);
  } else {
    for (int u = 0; u < 256; ++u) s += ld(bc + u) * ld(Wv + (size_t)u * 256 + m);
    s += ld(bv + m);
  }
  tmp[i * 256 + m] = s;
}

// Wcvo[i][m] = (tmp[0:8]@Wo)[i][m]; bcvo[m] = (tmp[8]@Wo)[m] + bo[m]
template <class T, int WANT>
__global__ void k_cvo_b(const int* __restrict__ flag, const float* __restrict__ tmp,
                        const T* __restrict__ Wo, const T* __restrict__ bo,
                        float* __restrict__ Wcvo, float* __restrict__ bcvo) {
  if (*flag != WANT) return;
  int i = blockIdx.x;   // 0..8
  int m = threadIdx.x;  // 0..255
  float s = 0.f;
  const float* tr = tmp + i * 256;
  for (int u = 0; u < 256; ++u) s += tr[u] * ld(Wo + (size_t)u * 256 + m);
  if (i < 8) Wcvo[i * 256 + m] = s;
  else       bcvo[m] = s + ld(bo + m);
}

// ---------------- block-wide sum of (v, v^2) over 256 threads ----------------
__device__ __forceinline__ void bsum2(float& s, float& q, float* sRed, int t) {
#pragma unroll
  for (int m = 1; m < 64; m <<= 1) { s += __shfl_xor(s, m); q += __shfl_xor(q, m); }
  if ((t & 63) == 0) { sRed[t >> 6] = s; sRed[4 + (t >> 6)] = q; }
  __syncthreads();
  s = sRed[0] + sRed[1] + sRed[2] + sRed[3];
  q = sRed[4] + sRed[5] + sRed[6] + sRed[7];
  __syncthreads();  // sRed reused by the next bsum2
}

// ---------------- one row per block, 256 threads, f32 math ----------------
template <class T, int WANT>
__global__ __launch_bounds__(256) void k_row(
    const int* __restrict__ flag,
    const T* __restrict__ node_i, const T* __restrict__ node_j,
    const T* __restrict__ latent, const T* __restrict__ hin, const int* __restrict__ tok,
    const T* __restrict__ We, const T* __restrict__ be,
    const T* __restrict__ ge, const T* __restrict__ bee,
    const T* __restrict__ gn, const T* __restrict__ bn, const T* __restrict__ emb,
    const T* __restrict__ W_ih, const T* __restrict__ b_ih,
    const T* __restrict__ W_hh, const T* __restrict__ b_hh,
    const T* __restrict__ Wf, const T* __restrict__ bfb,
    const T* __restrict__ gf, const T* __restrict__ bff,
    const T* __restrict__ W1, const T* __restrict__ b1,
    const T* __restrict__ W2, const T* __restrict__ b2,
    const float* __restrict__ Wcvo, const float* __restrict__ bcvo,
    T* __restrict__ outL, T* __restrict__ outNH) {
  if (*flag != WANT) return;
  __shared__ float sEdge[HD], sAtt[HD], sNewh[HD], sFused[HD], sL1[128], sRed[8];
  const int row = blockIdx.x, n = threadIdx.x;
  const size_t ro = (size_t)row * HD;

  // ---- edge = relu(LN([node_i|node_j] @ We + be)) ----
  float a = ld(be + n);
  for (int k = 0; k < HD; ++k) a += ld(node_i + ro + k) * ld(We + (size_t)k * HD + n);
  for (int k = 0; k < HD; ++k) a += ld(node_j + ro + k) * ld(We + (size_t)(HD + k) * HD + n);
  float s = a, q = a * a;
  bsum2(s, q, sRed, n);
  {
    float mean = s * (1.f / 256.f), var = q * (1.f / 256.f) - mean * mean;
    float rs = rsqrtf(var + 1e-5f);
    sEdge[n] = fmaxf((a - mean) * rs * ld(ge + n) + ld(bee + n), 0.f);
  }

  // ---- attended = LN(latent @ Wcvo + bcvo) ----
  a = bcvo[n];
#pragma unroll
  for (int k = 0; k < 8; ++k) a += ld(latent + (size_t)row * 8 + k) * Wcvo[k * HD + n];
  s = a; q = a * a;
  bsum2(s, q, sRed, n);
  {
    float mean = s * (1.f / 256.f), var = q * (1.f / 256.f) - mean * mean;
    float rs = rsqrtf(var + 1e-5f);
    sAtt[n] = (a - mean) * rs * ld(gn + n) + ld(bn + n);
  }
  __syncthreads();  // sAtt/sEdge visible to all

  // ---- GRU: gates packed [r|z|n]; x = [attended | emb[tok]] ----
  const int tk = tok[row];
  float gir = ld(b_ih + n), giz = ld(b_ih + 256 + n), gin = ld(b_ih + 512 + n);
  for (int k = 0; k < HD; ++k) {
    float x = sAtt[k];
    const T* wr = W_ih + (size_t)k * 768;
    gir += x * ld(wr + n); giz += x * ld(wr + 256 + n); gin += x * ld(wr + 512 + n);
  }
  for (int k = 0; k < HD; ++k) {
    float x = ld(emb + (size_t)tk * HD + k);
    const T* wr = W_ih + (size_t)(HD + k) * 768;
    gir += x * ld(wr + n); giz += x * ld(wr + 256 + n); gin += x * ld(wr + 512 + n);
  }
  float ghr = ld(b_hh + n), ghz = ld(b_hh + 256 + n), ghn = ld(b_hh + 512 + n);
  for (int k = 0; k < HD; ++k) {
    float x = ld(hin + ro + k);
    const T* wr = W_hh + (size_t)k * 768;
    ghr += x * ld(wr + n); ghz += x * ld(wr + 256 + n); ghn += x * ld(wr + 512 + n);
  }
  float r = 1.f / (1.f + expf(-(gir + ghr)));
  float z = 1.f / (1.f + expf(-(giz + ghz)));
  float nn = tanhf(gin + r * ghn);
  float hv = ld(hin + ro + n);
  float nh = (1.f - z) * nn + z * hv;
  sNewh[n] = nh;
  outNH[ro + n] = (T)nh;
  __syncthreads();

  // ---- fused = relu(LN([edge|att|newh] @ Wf + bf)) ----
  a = ld(bfb + n);
  for (int k = 0; k < HD; ++k) a += sEdge[k] * ld(Wf + (size_t)k * HD + n);
  for (int k = 0; k < HD; ++k) a += sAtt[k] * ld(Wf + (size_t)(HD + k) * HD + n);
  for (int k = 0; k < HD; ++k) a += sNewh[k] * ld(Wf + (size_t)(512 + k) * HD + n);
  s = a; q = a * a;
  bsum2(s, q, sRed, n);
  {
    float mean = s * (1.f / 256.f), var = q * (1.f / 256.f) - mean * mean;
    float rs = rsqrtf(var + 1e-5f);
    sFused[n] = fmaxf((a - mean) * rs * ld(gf + n) + ld(bff + n), 0.f);
  }
  __syncthreads();

  // ---- head: logits = relu(fused @ W1 + b1) @ W2 + b2 ----
  if (n < 128) {
    float h1 = ld(b1 + n);
    for (int k = 0; k < HD; ++k) h1 += sFused[k] * ld(W1 + (size_t)k * 128 + n);
    sL1[n] = fmaxf(h1, 0.f);
  }
  __syncthreads();
  if (n < 8) {
    float lg = ld(b2 + n);
    for (int k = 0; k < 128; ++k) lg += sL1[k] * ld(W2 + (size_t)k * 8 + n);
    outL[(size_t)row * 8 + n] = (T)lg;
  }
}

// ---------------- launch ----------------

template <class T, int WANT>
static void launch_variant(void* const* d_in, int B, void* d_out, char* ws, hipStream_t stream) {
  const int* flag = (const int*)ws;
  float* tmpcv = (float*)(ws + 1024);   // 9*256 f32 = 9216 B
  float* Wcvo  = (float*)(ws + 16384);  // 8*256 f32 = 8192 B
  float* bcvo  = (float*)(ws + 24576);  // 256 f32

  const T* node_i = (const T*)d_in[0];
  const T* node_j = (const T*)d_in[1];
  const T* latent = (const T*)d_in[2];
  const T* hin    = (const T*)d_in[3];
  const int* tok  = (const int*)d_in[4];
  const T* We  = (const T*)d_in[5];
  const T* be  = (const T*)d_in[6];
  const T* ge  = (const T*)d_in[7];
  const T* bee = (const T*)d_in[8];
  const T* Wc  = (const T*)d_in[9];
  const T* bc  = (const T*)d_in[10];
  // 11..14: Wq,bq,Wk,bk — inert (softmax over one key == 1)
  const T* Wv  = (const T*)d_in[15];
  const T* bv  = (const T*)d_in[16];
  const T* Wo  = (const T*)d_in[17];
  const T* bo  = (const T*)d_in[18];
  const T* gn  = (const T*)d_in[19];
  const T* bn  = (const T*)d_in[20];
  const T* emb = (const T*)d_in[21];
  const T* W_ih = (const T*)d_in[22];
  const T* b_ih = (const T*)d_in[23];
  const T* W_hh = (const T*)d_in[24];
  const T* b_hh = (const T*)d_in[25];
  const T* Wf  = (const T*)d_in[26];
  const T* bfb = (const T*)d_in[27];
  const T* gf  = (const T*)d_in[28];
  const T* bff = (const T*)d_in[29];
  const T* W1  = (const T*)d_in[30];
  const T* b1  = (const T*)d_in[31];
  const T* W2  = (const T*)d_in[32];
  const T* b2  = (const T*)d_in[33];

  T* outL  = (T*)d_out;
  T* outNH = outL + (size_t)B * 8;

  k_cvo_a<T, WANT><<<9, 256, 0, stream>>>(flag, Wc, Wv, bc, bv, tmpcv);
  k_cvo_b<T, WANT><<<9, 256, 0, stream>>>(flag, tmpcv, Wo, bo, Wcvo, bcvo);
  k_row<T, WANT><<<B, 256, 0, stream>>>(
      flag, node_i, node_j, latent, hin, tok,
      We, be, ge, bee, gn, bn, emb,
      W_ih, b_ih, W_hh, b_hh, Wf, bfb, gf, bff,
      W1, b1, W2, b2, Wcvo, bcvo, outL, outNH);
}

extern "C" void kernel_launch(void* const* d_in, const int* in_sizes, int n_in,
                              void* d_out, int out_size, void* d_ws, size_t ws_size,
                              hipStream_t stream) {
  char* ws = (char*)d_ws;
  const int B = in_sizes[0] / HD;

  k_detect<<<1, 256, 0, stream>>>((const unsigned int*)d_in[0], (int*)ws);
  launch_variant<float, 0>(d_in, B, d_out, ws, stream);  // f32-in / f32-out world
  launch_variant<bf16, 1>(d_in, B, d_out, ws, stream);   // bf16-in / bf16-out world
}